// Round 1
// 588.144 us; speedup vs baseline: 1.1856x; 1.1856x over previous
//
#include <hip/hip_runtime.h>
#include <hip/hip_bf16.h>

#define BB 4
#define LL 256
#define PP 1024
#define DD 512
#define HH 8
#define HD 64
#define NRBF 50

// ---------------------------------------------------------------------------
// dtype helpers (inputs are fp32 per reference; bf16 fallback kept for safety)
// ---------------------------------------------------------------------------
__device__ __forceinline__ float bf2f(unsigned short u) {
  return __uint_as_float((unsigned)u << 16);
}

__device__ __forceinline__ float ldf(const void* p, size_t i, bool f32) {
  if (f32) return ((const float*)p)[i];
  return bf2f(((const unsigned short*)p)[i]);
}

__device__ __forceinline__ float4 ld4e(const void* p, size_t i, bool f32) {
  if (f32) return *(const float4*)((const float*)p + i);
  ushort4 u = *(const ushort4*)((const unsigned short*)p + i);
  float4 r;
  r.x = bf2f(u.x); r.y = bf2f(u.y); r.z = bf2f(u.z); r.w = bf2f(u.w);
  return r;
}

__global__ __launch_bounds__(256) void detect_dtype(const float* q, int* flag) {
  __shared__ int cnt;
  if (threadIdx.x == 0) cnt = 0;
  __syncthreads();
  int c = 0;
  for (int i = threadIdx.x; i < 1024; i += 256) {
    unsigned u = __float_as_uint(q[i]);
    unsigned e = (u >> 23) & 0xffu;
    if (e >= 104u && e <= 140u) c++;
  }
  atomicAdd(&cnt, c);
  __syncthreads();
  if (threadIdx.x == 0) *flag = (cnt > 512) ? 1 : 0;
}

// ---------------------------------------------------------------------------
// 128x128-tile fp32 GEMM core, 8x8 per thread (quad-split), double-buffered.
// mode 0: Y[m][512] = X@W + bias        (normal row-major)
// mode 1: Kt[b][h][d][p] transposed head-major output (m = b*1024+p, n=h*64+d)
// LDS: lds[0..4095] = As[2][16][128], lds[4096..8191] = Bs[2][16][128]
// ---------------------------------------------------------------------------
__device__ void gemm128(const void* __restrict__ X, const void* __restrict__ W,
                        const void* __restrict__ bias, float* __restrict__ Y,
                        const int bm, const int bn, const int mode,
                        const bool f32, float* lds) {
  const int tid = threadIdx.x;
  const int tx = tid & 15, ty = tid >> 4;
  const int lr = tid >> 1, lc = (tid & 1) * 8;   // A staging: row, col0
  const int wk = tid >> 5, wc = (tid & 31) * 4;  // B staging: k-row, col
  float acc[8][8] = {};
  float4 ra0, ra1, rb0, rb1;

  // prologue: tile 0 -> regs -> buf 0
  ra0 = ld4e(X, (size_t)(bm + lr) * 512 + lc, f32);
  ra1 = ld4e(X, (size_t)(bm + lr) * 512 + lc + 4, f32);
  rb0 = ld4e(W, (size_t)wk * 512 + bn + wc, f32);
  rb1 = ld4e(W, (size_t)(wk + 8) * 512 + bn + wc, f32);
  {
    float* Ab = lds;
    float* Bb = lds + 4096;
    Ab[(lc + 0) * 128 + lr] = ra0.x; Ab[(lc + 1) * 128 + lr] = ra0.y;
    Ab[(lc + 2) * 128 + lr] = ra0.z; Ab[(lc + 3) * 128 + lr] = ra0.w;
    Ab[(lc + 4) * 128 + lr] = ra1.x; Ab[(lc + 5) * 128 + lr] = ra1.y;
    Ab[(lc + 6) * 128 + lr] = ra1.z; Ab[(lc + 7) * 128 + lr] = ra1.w;
    *(float4*)&Bb[wk * 128 + wc] = rb0;
    *(float4*)&Bb[(wk + 8) * 128 + wc] = rb1;
  }
  __syncthreads();

  int buf = 0;
  for (int tt = 0; tt < 32; ++tt) {
    if (tt < 31) {  // issue next tile's global loads (overlap with compute)
      const int k0 = (tt + 1) * 16;
      ra0 = ld4e(X, (size_t)(bm + lr) * 512 + k0 + lc, f32);
      ra1 = ld4e(X, (size_t)(bm + lr) * 512 + k0 + lc + 4, f32);
      rb0 = ld4e(W, (size_t)(k0 + wk) * 512 + bn + wc, f32);
      rb1 = ld4e(W, (size_t)(k0 + wk + 8) * 512 + bn + wc, f32);
    }
    {
      const float* Ab = lds + buf * 2048;
      const float* Bb = lds + 4096 + buf * 2048;
#pragma unroll
      for (int k = 0; k < 16; ++k) {
        float4 aL = *(const float4*)&Ab[k * 128 + ty * 4];
        float4 aH = *(const float4*)&Ab[k * 128 + 64 + ty * 4];
        float4 bL = *(const float4*)&Bb[k * 128 + tx * 4];
        float4 bH = *(const float4*)&Bb[k * 128 + 64 + tx * 4];
        const float a8[8] = {aL.x, aL.y, aL.z, aL.w, aH.x, aH.y, aH.z, aH.w};
        const float b8[8] = {bL.x, bL.y, bL.z, bL.w, bH.x, bH.y, bH.z, bH.w};
#pragma unroll
        for (int i = 0; i < 8; ++i)
#pragma unroll
          for (int j = 0; j < 8; ++j)
            acc[i][j] = fmaf(a8[i], b8[j], acc[i][j]);
      }
    }
    if (tt < 31) {  // stage next tile into the other buffer
      float* Ab = lds + (buf ^ 1) * 2048;
      float* Bb = lds + 4096 + (buf ^ 1) * 2048;
      Ab[(lc + 0) * 128 + lr] = ra0.x; Ab[(lc + 1) * 128 + lr] = ra0.y;
      Ab[(lc + 2) * 128 + lr] = ra0.z; Ab[(lc + 3) * 128 + lr] = ra0.w;
      Ab[(lc + 4) * 128 + lr] = ra1.x; Ab[(lc + 5) * 128 + lr] = ra1.y;
      Ab[(lc + 6) * 128 + lr] = ra1.z; Ab[(lc + 7) * 128 + lr] = ra1.w;
      *(float4*)&Bb[wk * 128 + wc] = rb0;
      *(float4*)&Bb[(wk + 8) * 128 + wc] = rb1;
    }
    __syncthreads();
    buf ^= 1;
  }

  if (mode == 0) {
#pragma unroll
    for (int rh = 0; rh < 2; ++rh)
#pragma unroll
      for (int i = 0; i < 4; ++i) {
        const int r = bm + rh * 64 + ty * 4 + i;
#pragma unroll
        for (int ch = 0; ch < 2; ++ch) {
          const int c = bn + ch * 64 + tx * 4;
          float4 o;
          o.x = acc[rh * 4 + i][ch * 4 + 0] + ldf(bias, c + 0, f32);
          o.y = acc[rh * 4 + i][ch * 4 + 1] + ldf(bias, c + 1, f32);
          o.z = acc[rh * 4 + i][ch * 4 + 2] + ldf(bias, c + 2, f32);
          o.w = acc[rh * 4 + i][ch * 4 + 3] + ldf(bias, c + 3, f32);
          *(float4*)&Y[(size_t)r * 512 + c] = o;
        }
      }
  } else {
    const int bq = bm >> 10;
    const int pb = bm & 1023;
#pragma unroll
    for (int ch = 0; ch < 2; ++ch)
#pragma unroll
      for (int j = 0; j < 4; ++j) {
        const int c = bn + ch * 64 + tx * 4 + j;  // h = c>>6, d = c&63
        const float bb = ldf(bias, c, f32);
#pragma unroll
        for (int rh = 0; rh < 2; ++rh) {
          float4 pv;
          pv.x = acc[rh * 4 + 0][ch * 4 + j] + bb;
          pv.y = acc[rh * 4 + 1][ch * 4 + j] + bb;
          pv.z = acc[rh * 4 + 2][ch * 4 + j] + bb;
          pv.w = acc[rh * 4 + 3][ch * 4 + j] + bb;
          const int p0 = pb + rh * 64 + ty * 4;
          *(float4*)&Y[(((size_t)bq * 8 + (c >> 6)) * 64 + (c & 63)) * 1024 +
                       p0] = pv;
        }
      }
  }
}

// ---------------------------------------------------------------------------
// Fused Q/K/V projections + rbf bias in ONE launch.
// blocks 0..31:   Q-proj  (M=1024, mode 0)
// blocks 32..159: K-proj  (M=4096, mode 1 -> Kt[b][h][d][p])
// blocks 160..287:V-proj  (M=4096, mode 0)
// blocks 288..4383: rbf bias rows (memory-bound; fills idle CUs)
// ---------------------------------------------------------------------------
__global__ __launch_bounds__(256) void fused_qkvr(
    const void* __restrict__ query, const void* __restrict__ key,
    const void* __restrict__ value, const void* __restrict__ Wq,
    const void* __restrict__ bq_, const void* __restrict__ Wk,
    const void* __restrict__ bk_, const void* __restrict__ Wv,
    const void* __restrict__ bv_, const void* __restrict__ rbf,
    const void* __restrict__ Wr, const void* __restrict__ br_,
    float* __restrict__ Qw, float* __restrict__ Ktw, float* __restrict__ Vw,
    float* __restrict__ biasW, const int* __restrict__ flag) {
  __shared__ float lds[8192];  // 32 KB: GEMM double buffers / rbf weights
  const bool f32 = (*flag != 0);
  const int blk = blockIdx.x;

  if (blk < 288) {
    const void *X, *W, *bias;
    float* Y;
    int mode, mi, ni;
    if (blk < 32) {
      X = query; W = Wq; bias = bq_; Y = Qw; mode = 0;
      mi = blk >> 2; ni = blk & 3;
    } else if (blk < 160) {
      const int q2 = blk - 32;
      X = key; W = Wk; bias = bk_; Y = Ktw; mode = 1;
      mi = q2 >> 2; ni = q2 & 3;
    } else {
      const int q2 = blk - 160;
      X = value; W = Wv; bias = bv_; Y = Vw; mode = 0;
      mi = q2 >> 2; ni = q2 & 3;
    }
    gemm128(X, W, bias, Y, mi * 128, ni * 128, mode, f32, lds);
    return;
  }

  // ---- rbf bias: biasW[b,l,h,p] = rbf[b,l,p,:] @ Wr[:,h] + br[h] ----
  float* wrS = lds;        // 400 floats
  float* brS = lds + 404;  // 8 floats
  const int tid = threadIdx.x;
  for (int i = tid; i < NRBF * 8; i += 256) wrS[i] = ldf(Wr, i, f32);
  if (tid < 8) brS[tid] = ldf(br_, tid, f32);
  __syncthreads();
  const size_t row = (size_t)(blk - 288) * 256 + tid;  // (b*L+l)*P + p
  float acc[8];
#pragma unroll
  for (int h = 0; h < 8; ++h) acc[h] = brS[h];
  if (f32) {
    const float2* rp = (const float2*)((const float*)rbf + row * NRBF);
#pragma unroll
    for (int j = 0; j < 25; ++j) {
      float2 r2 = rp[j];
      float4 wa = *(const float4*)&wrS[(2 * j) * 8];
      float4 wb = *(const float4*)&wrS[(2 * j) * 8 + 4];
      float4 wc = *(const float4*)&wrS[(2 * j + 1) * 8];
      float4 wd = *(const float4*)&wrS[(2 * j + 1) * 8 + 4];
      acc[0] = fmaf(r2.x, wa.x, acc[0]); acc[1] = fmaf(r2.x, wa.y, acc[1]);
      acc[2] = fmaf(r2.x, wa.z, acc[2]); acc[3] = fmaf(r2.x, wa.w, acc[3]);
      acc[4] = fmaf(r2.x, wb.x, acc[4]); acc[5] = fmaf(r2.x, wb.y, acc[5]);
      acc[6] = fmaf(r2.x, wb.z, acc[6]); acc[7] = fmaf(r2.x, wb.w, acc[7]);
      acc[0] = fmaf(r2.y, wc.x, acc[0]); acc[1] = fmaf(r2.y, wc.y, acc[1]);
      acc[2] = fmaf(r2.y, wc.z, acc[2]); acc[3] = fmaf(r2.y, wc.w, acc[3]);
      acc[4] = fmaf(r2.y, wd.x, acc[4]); acc[5] = fmaf(r2.y, wd.y, acc[5]);
      acc[6] = fmaf(r2.y, wd.z, acc[6]); acc[7] = fmaf(r2.y, wd.w, acc[7]);
    }
  } else {
    const unsigned short* rb = (const unsigned short*)rbf + row * NRBF;
#pragma unroll
    for (int j = 0; j < NRBF; ++j) {
      float r = bf2f(rb[j]);
#pragma unroll
      for (int h = 0; h < 8; ++h) acc[h] = fmaf(r, wrS[j * 8 + h], acc[h]);
    }
  }
  const size_t bl = row >> 10;
  const int p = (int)(row & 1023);
#pragma unroll
  for (int h = 0; h < 8; ++h) biasW[(bl * 8 + h) * 1024 + p] = acc[h];
}

// ---------------------------------------------------------------------------
// Attention v6: 2 queries per block, 512 threads. Each K/V float4 is loaded
// once and used for BOTH queries -> L2 traffic halves (was the bottleneck:
// 4 GB L2 @ ~22 TB/s). Scores padded to stride 1028 (PV per-head broadcast
// reads land on distinct banks). PV partials alias scores LDS after a sync
// -> 68 KB LDS -> 2 blocks/CU (16 waves/CU).
// ---------------------------------------------------------------------------
#define SST 1028  // padded score stride

__global__ __launch_bounds__(512) void attn_v6(
    const float* __restrict__ Q,     // [B*L, 512]
    const float* __restrict__ Kt,    // [B][8][64][1024]
    const float* __restrict__ V,     // [B*P, 512]
    const float* __restrict__ biasW, // [B*L][8][1024]
    const int* __restrict__ mask,    // [B,P]
    float* __restrict__ AO,          // [B*L, 512]
    void* __restrict__ d_out, const int* __restrict__ flag) {
  const int xcd = blockIdx.x & 7;
  const int idx = blockIdx.x >> 3;          // 0..63
  const int b = xcd >> 1;
  const int lp = ((xcd & 1) << 6) | idx;    // 0..127
  const int bl0 = b * LL + lp * 2;          // first of 2 queries
  const int t = threadIdx.x;
  const bool f32 = (*flag != 0);

  __shared__ float qS[2][512];              // 4 KB
  __shared__ float scoresS[2][8 * SST];     // 65.8 KB

  for (int i = t; i < 1024; i += 512)
    qS[i >> 9][i & 511] = Q[(size_t)bl0 * 512 + i];
  __syncthreads();

  // ---- scores: thread owns p-quad tq, head-half hh; both queries ----
  {
    const int tq = t & 255;
    const int hh = t >> 8;
    const int4 mk4 = *(const int4*)(mask + b * PP + 4 * tq);
#pragma unroll 1
    for (int hi = 0; hi < 4; ++hi) {
      const int h = hh * 4 + hi;
      const float4* ktp =
          (const float4*)(Kt + ((size_t)b * 8 + h) * 64 * 1024) + tq;
      float4 a0 = {0.f, 0.f, 0.f, 0.f}, a1 = {0.f, 0.f, 0.f, 0.f};
#pragma unroll 2
      for (int dq = 0; dq < 16; ++dq) {
        float4 qa = *(const float4*)&qS[0][h * 64 + dq * 4];  // bcast
        float4 qb = *(const float4*)&qS[1][h * 64 + dq * 4];
        float4 k0 = ktp[(size_t)(dq * 4 + 0) * 256];
        float4 k1 = ktp[(size_t)(dq * 4 + 1) * 256];
        float4 k2 = ktp[(size_t)(dq * 4 + 2) * 256];
        float4 k3 = ktp[(size_t)(dq * 4 + 3) * 256];
        a0.x = fmaf(qa.x, k0.x, a0.x); a0.y = fmaf(qa.x, k0.y, a0.y);
        a0.z = fmaf(qa.x, k0.z, a0.z); a0.w = fmaf(qa.x, k0.w, a0.w);
        a0.x = fmaf(qa.y, k1.x, a0.x); a0.y = fmaf(qa.y, k1.y, a0.y);
        a0.z = fmaf(qa.y, k1.z, a0.z); a0.w = fmaf(qa.y, k1.w, a0.w);
        a0.x = fmaf(qa.z, k2.x, a0.x); a0.y = fmaf(qa.z, k2.y, a0.y);
        a0.z = fmaf(qa.z, k2.z, a0.z); a0.w = fmaf(qa.z, k2.w, a0.w);
        a0.x = fmaf(qa.w, k3.x, a0.x); a0.y = fmaf(qa.w, k3.y, a0.y);
        a0.z = fmaf(qa.w, k3.z, a0.z); a0.w = fmaf(qa.w, k3.w, a0.w);
        a1.x = fmaf(qb.x, k0.x, a1.x); a1.y = fmaf(qb.x, k0.y, a1.y);
        a1.z = fmaf(qb.x, k0.z, a1.z); a1.w = fmaf(qb.x, k0.w, a1.w);
        a1.x = fmaf(qb.y, k1.x, a1.x); a1.y = fmaf(qb.y, k1.y, a1.y);
        a1.z = fmaf(qb.y, k1.z, a1.z); a1.w = fmaf(qb.y, k1.w, a1.w);
        a1.x = fmaf(qb.z, k2.x, a1.x); a1.y = fmaf(qb.z, k2.y, a1.y);
        a1.z = fmaf(qb.z, k2.z, a1.z); a1.w = fmaf(qb.z, k2.w, a1.w);
        a1.x = fmaf(qb.w, k3.x, a1.x); a1.y = fmaf(qb.w, k3.y, a1.y);
        a1.z = fmaf(qb.w, k3.z, a1.z); a1.w = fmaf(qb.w, k3.w, a1.w);
      }
      float4 b40 =
          *(const float4*)&biasW[((size_t)bl0 * 8 + h) * 1024 + 4 * tq];
      float4 b41 =
          *(const float4*)&biasW[((size_t)(bl0 + 1) * 8 + h) * 1024 + 4 * tq];
      float4 s0, s1;
      s0.x = (mk4.x == 0) ? -1e9f : fmaf(a0.x, 0.125f, b40.x);
      s0.y = (mk4.y == 0) ? -1e9f : fmaf(a0.y, 0.125f, b40.y);
      s0.z = (mk4.z == 0) ? -1e9f : fmaf(a0.z, 0.125f, b40.z);
      s0.w = (mk4.w == 0) ? -1e9f : fmaf(a0.w, 0.125f, b40.w);
      s1.x = (mk4.x == 0) ? -1e9f : fmaf(a1.x, 0.125f, b41.x);
      s1.y = (mk4.y == 0) ? -1e9f : fmaf(a1.y, 0.125f, b41.y);
      s1.z = (mk4.z == 0) ? -1e9f : fmaf(a1.z, 0.125f, b41.z);
      s1.w = (mk4.w == 0) ? -1e9f : fmaf(a1.w, 0.125f, b41.w);
      *(float4*)&scoresS[0][h * SST + 4 * tq] = s0;
      *(float4*)&scoresS[1][h * SST + 4 * tq] = s1;
    }
  }
  __syncthreads();

  // ---- softmax over P: 16 (q,h) rows, 2 per wave ----
  {
    const int wave = t >> 6, lane = t & 63;
    for (int pr = wave * 2; pr < wave * 2 + 2; ++pr) {
      float* sc = &scoresS[pr >> 3][(pr & 7) * SST];
      float m = -3.0e38f;
      for (int i = lane; i < PP; i += 64) m = fmaxf(m, sc[i]);
#pragma unroll
      for (int off = 32; off; off >>= 1) m = fmaxf(m, __shfl_xor(m, off, 64));
      float sum = 0.f;
      for (int i = lane; i < PP; i += 64) {
        float e = __expf(sc[i] - m);
        sc[i] = e;
        sum += e;
      }
#pragma unroll
      for (int off = 32; off; off >>= 1) sum += __shfl_xor(sum, off, 64);
      const float inv = 1.0f / sum;
      for (int i = lane; i < PP; i += 64) sc[i] *= inv;
    }
  }
  __syncthreads();

  // ---- attn_mean: q = t>>8, p-quad = t&255 ----
  {
    const int q = t >> 8, pq = t & 255;
    float4 s = {0.f, 0.f, 0.f, 0.f};
#pragma unroll
    for (int h = 0; h < 8; ++h) {
      float4 v = *(const float4*)&scoresS[q][h * SST + 4 * pq];
      s.x += v.x; s.y += v.y; s.z += v.z; s.w += v.w;
    }
    s.x *= 0.125f; s.y *= 0.125f; s.z *= 0.125f; s.w *= 0.125f;
    const size_t base =
        (size_t)BB * LL * DD + (size_t)(bl0 + q) * PP + 4 * pq;
    if (f32) {
      *(float4*)((float*)d_out + base) = s;
    } else {
      __hip_bfloat16* o1 = (__hip_bfloat16*)d_out;
      o1[base + 0] = __float2bfloat16(s.x);
      o1[base + 1] = __float2bfloat16(s.y);
      o1[base + 2] = __float2bfloat16(s.z);
      o1[base + 3] = __float2bfloat16(s.w);
    }
  }

  // ---- PV: thread owns c-quad (cq) and p-quarter (ph); both queries ----
  float4 pa0, pa1;
  {
    const int cq = t & 127;
    const int ph = t >> 7;  // 0..3, 256 p each
    const int h = cq >> 4;
    const float* sc0 = &scoresS[0][h * SST];
    const float* sc1 = &scoresS[1][h * SST];
    const float4* Vb = (const float4*)(V + (size_t)b * PP * 512) + cq;
    float4 A0 = {0.f, 0.f, 0.f, 0.f}, A1 = {0.f, 0.f, 0.f, 0.f};
    const int p0 = ph * 256;
#pragma unroll 2
    for (int p4 = p0; p4 < p0 + 256; p4 += 4) {
      float4 pr0 = *(const float4*)&sc0[p4];
      float4 pr1 = *(const float4*)&sc1[p4];
      float4 v0 = Vb[(size_t)(p4 + 0) * 128];
      float4 v1 = Vb[(size_t)(p4 + 1) * 128];
      float4 v2 = Vb[(size_t)(p4 + 2) * 128];
      float4 v3 = Vb[(size_t)(p4 + 3) * 128];
      A0.x = fmaf(pr0.x, v0.x, A0.x); A0.y = fmaf(pr0.x, v0.y, A0.y);
      A0.z = fmaf(pr0.x, v0.z, A0.z); A0.w = fmaf(pr0.x, v0.w, A0.w);
      A0.x = fmaf(pr0.y, v1.x, A0.x); A0.y = fmaf(pr0.y, v1.y, A0.y);
      A0.z = fmaf(pr0.y, v1.z, A0.z); A0.w = fmaf(pr0.y, v1.w, A0.w);
      A0.x = fmaf(pr0.z, v2.x, A0.x); A0.y = fmaf(pr0.z, v2.y, A0.y);
      A0.z = fmaf(pr0.z, v2.z, A0.z); A0.w = fmaf(pr0.z, v2.w, A0.w);
      A0.x = fmaf(pr0.w, v3.x, A0.x); A0.y = fmaf(pr0.w, v3.y, A0.y);
      A0.z = fmaf(pr0.w, v3.z, A0.z); A0.w = fmaf(pr0.w, v3.w, A0.w);
      A1.x = fmaf(pr1.x, v0.x, A1.x); A1.y = fmaf(pr1.x, v0.y, A1.y);
      A1.z = fmaf(pr1.x, v0.z, A1.z); A1.w = fmaf(pr1.x, v0.w, A1.w);
      A1.x = fmaf(pr1.y, v1.x, A1.x); A1.y = fmaf(pr1.y, v1.y, A1.y);
      A1.z = fmaf(pr1.y, v1.z, A1.z); A1.w = fmaf(pr1.y, v1.w, A1.w);
      A1.x = fmaf(pr1.z, v2.x, A1.x); A1.y = fmaf(pr1.z, v2.y, A1.y);
      A1.z = fmaf(pr1.z, v2.z, A1.z); A1.w = fmaf(pr1.z, v2.w, A1.w);
      A1.x = fmaf(pr1.w, v3.x, A1.x); A1.y = fmaf(pr1.w, v3.y, A1.y);
      A1.z = fmaf(pr1.w, v3.z, A1.z); A1.w = fmaf(pr1.w, v3.w, A1.w);
    }
    pa0 = A0;
    pa1 = A1;
  }
  __syncthreads();  // all score reads complete; safe to reuse LDS
  {
    const int cq = t & 127, ph = t >> 7;
    float* parts = &scoresS[0][0];  // [2 q][4 ph][128 cq][4] = 16 KB alias
    *(float4*)&parts[((0 * 4 + ph) * 128 + cq) * 4] = pa0;
    *(float4*)&parts[((1 * 4 + ph) * 128 + cq) * 4] = pa1;
  }
  __syncthreads();
  if (t < 256) {
    const int q = t >> 7, c = t & 127;
    const float* parts = &scoresS[0][0];
    float4 a = *(const float4*)&parts[((q * 4 + 0) * 128 + c) * 4];
#pragma unroll
    for (int ph = 1; ph < 4; ++ph) {
      float4 x = *(const float4*)&parts[((q * 4 + ph) * 128 + c) * 4];
      a.x += x.x; a.y += x.y; a.z += x.z; a.w += x.w;
    }
    *(float4*)&AO[(size_t)(bl0 + q) * 512 + 4 * c] = a;
  }
}

// ---------------------------------------------------------------------------
// Output projection + residual: Xout = AO@Wo + bo + query   (fp32 ws)
// ---------------------------------------------------------------------------
__global__ __launch_bounds__(256) void proj_out(
    const float* __restrict__ X, const void* __restrict__ W,
    const void* __restrict__ bias, const void* __restrict__ resid,
    float* __restrict__ Y, const int* __restrict__ flag) {
  __shared__ float As[16][64];
  __shared__ float Bs[16][64];
  const bool f32 = (*flag != 0);
  const int bm = blockIdx.x * 64, bn = blockIdx.y * 64;
  const int tid = threadIdx.x;
  const int tx = tid & 15, ty = tid >> 4;
  float acc[4][4] = {};
  for (int k0 = 0; k0 < 512; k0 += 16) {
    {
      int r = tid >> 2, kf = (tid & 3) * 4;
      float4 x4 = *(const float4*)(X + (size_t)(bm + r) * 512 + k0 + kf);
      As[kf + 0][r] = x4.x; As[kf + 1][r] = x4.y;
      As[kf + 2][r] = x4.z; As[kf + 3][r] = x4.w;
    }
    if (f32) {
      int kk = tid >> 4, cf = (tid & 15) * 4;
      *(float4*)&Bs[kk][cf] =
          *(const float4*)((const float*)W + (size_t)(k0 + kk) * 512 + bn + cf);
    } else {
      const unsigned short* Wb = (const unsigned short*)W;
      for (int f = tid; f < 16 * 64; f += 256) {
        int kk = f >> 6, c = f & 63;
        Bs[kk][c] = bf2f(Wb[(size_t)(k0 + kk) * 512 + bn + c]);
      }
    }
    __syncthreads();
#pragma unroll
    for (int k = 0; k < 16; ++k) {
      float4 a4 = *(const float4*)&As[k][ty * 4];
      float4 b4 = *(const float4*)&Bs[k][tx * 4];
      acc[0][0] = fmaf(a4.x, b4.x, acc[0][0]); acc[0][1] = fmaf(a4.x, b4.y, acc[0][1]);
      acc[0][2] = fmaf(a4.x, b4.z, acc[0][2]); acc[0][3] = fmaf(a4.x, b4.w, acc[0][3]);
      acc[1][0] = fmaf(a4.y, b4.x, acc[1][0]); acc[1][1] = fmaf(a4.y, b4.y, acc[1][1]);
      acc[1][2] = fmaf(a4.y, b4.z, acc[1][2]); acc[1][3] = fmaf(a4.y, b4.w, acc[1][3]);
      acc[2][0] = fmaf(a4.z, b4.x, acc[2][0]); acc[2][1] = fmaf(a4.z, b4.y, acc[2][1]);
      acc[2][2] = fmaf(a4.z, b4.z, acc[2][2]); acc[2][3] = fmaf(a4.z, b4.w, acc[2][3]);
      acc[3][0] = fmaf(a4.w, b4.x, acc[3][0]); acc[3][1] = fmaf(a4.w, b4.y, acc[3][1]);
      acc[3][2] = fmaf(a4.w, b4.z, acc[3][2]); acc[3][3] = fmaf(a4.w, b4.w, acc[3][3]);
    }
    __syncthreads();
  }
#pragma unroll
  for (int i = 0; i < 4; ++i) {
    int r = bm + ty * 4 + i;
    float4 o;
#pragma unroll
    for (int j = 0; j < 4; ++j) {
      int c = bn + tx * 4 + j;
      float v = acc[i][j] + ldf(bias, c, f32) +
                ldf(resid, (size_t)r * 512 + c, f32);
      ((float*)&o)[j] = v;
    }
    *(float4*)(Y + (size_t)r * 512 + bn + tx * 4) = o;
  }
}

// ---------------------------------------------------------------------------
// LayerNorm rows of Xw -> out0
// ---------------------------------------------------------------------------
__global__ __launch_bounds__(256) void ln_kernel(
    const float* __restrict__ Xw, const void* __restrict__ gamma,
    const void* __restrict__ beta, void* __restrict__ d_out,
    const int* __restrict__ flag) {
  const int bl = blockIdx.x;
  const int tid = threadIdx.x;
  const bool f32 = (*flag != 0);
  __shared__ float red[16];
  float v0 = Xw[(size_t)bl * 512 + tid];
  float v1 = Xw[(size_t)bl * 512 + tid + 256];
  float s = v0 + v1, s2 = v0 * v0 + v1 * v1;
#pragma unroll
  for (int off = 32; off; off >>= 1) {
    s += __shfl_xor(s, off, 64);
    s2 += __shfl_xor(s2, off, 64);
  }
  const int wave = tid >> 6, lane = tid & 63;
  if (lane == 0) { red[wave] = s; red[8 + wave] = s2; }
  __syncthreads();
  if (tid == 0) {
    float ts = 0.f, ts2 = 0.f;
    for (int w = 0; w < 4; ++w) { ts += red[w]; ts2 += red[8 + w]; }
    red[0] = ts; red[1] = ts2;
  }
  __syncthreads();
  const float mu = red[0] * (1.0f / 512.0f);
  const float var = red[1] * (1.0f / 512.0f) - mu * mu;
  const float rstd = rsqrtf(var + 1e-5f);
  float o0 = (v0 - mu) * rstd * ldf(gamma, tid, f32) + ldf(beta, tid, f32);
  float o1 = (v1 - mu) * rstd * ldf(gamma, tid + 256, f32) +
             ldf(beta, tid + 256, f32);
  if (f32) {
    float* o = (float*)d_out;
    o[(size_t)bl * 512 + tid] = o0;
    o[(size_t)bl * 512 + tid + 256] = o1;
  } else {
    __hip_bfloat16* o = (__hip_bfloat16*)d_out;
    o[(size_t)bl * 512 + tid] = __float2bfloat16(o0);
    o[(size_t)bl * 512 + tid + 256] = __float2bfloat16(o1);
  }
}

// ---------------------------------------------------------------------------
extern "C" void kernel_launch(void* const* d_in, const int* in_sizes, int n_in,
                              void* d_out, int out_size, void* d_ws,
                              size_t ws_size, hipStream_t stream) {
  const void* query = d_in[0];
  const void* key = d_in[1];
  const void* value = d_in[2];
  const void* rbf = d_in[3];
  const int* key_mask = (const int*)d_in[4];
  const void* Wq = d_in[5];
  const void* bq = d_in[6];
  const void* Wk = d_in[7];
  const void* bk = d_in[8];
  const void* Wv = d_in[9];
  const void* bv = d_in[10];
  const void* Wr = d_in[11];
  const void* br = d_in[12];
  const void* Wo = d_in[13];
  const void* bo = d_in[14];
  const void* gamma = d_in[15];
  const void* beta = d_in[16];

  // ws: [flag 16B] Q | Kt | V | AO | X | biasW
  int* flag = (int*)d_ws;
  float* base = (float*)d_ws + 4;
  float* Qw = base;
  float* Ktw = Qw + (size_t)BB * LL * DD;   // +524288
  float* Vw = Ktw + (size_t)BB * PP * DD;   // +2097152
  float* AO = Vw + (size_t)BB * PP * DD;    // +2097152
  float* Xw = AO + (size_t)BB * LL * DD;    // +524288
  float* biasW = Xw + (size_t)BB * LL * DD; // +524288

  detect_dtype<<<1, 256, 0, stream>>>((const float*)query, flag);
  // 288 GEMM tiles (Q:32, K:128, V:128) + 4096 rbf blocks in one launch
  fused_qkvr<<<dim3(288 + 4096), 256, 0, stream>>>(
      query, key, value, Wq, bq, Wk, bk, Wv, bv, rbf, Wr, br, Qw, Ktw, Vw,
      biasW, flag);
  attn_v6<<<dim3(BB * LL / 2), 512, 0, stream>>>(Qw, Ktw, Vw, biasW, key_mask,
                                                 AO, d_out, flag);
  proj_out<<<dim3(16, 8), 256, 0, stream>>>(AO, Wo, bo, query, Xw, flag);
  ln_kernel<<<dim3(BB * LL), 256, 0, stream>>>(Xw, gamma, beta, d_out, flag);
}